// Round 19
// baseline (95.332 us; speedup 1.0000x reference)
//
#include <hip/hip_runtime.h>
#include <hip/hip_bf16.h>

#define BB 32
#define CC 128
#define HH 96
#define WW 96
#define BN_EPS 1e-5f

typedef __attribute__((ext_vector_type(8))) short bf16x8_t;
typedef __attribute__((ext_vector_type(4))) float f32x4_t;
typedef __attribute__((ext_vector_type(4), aligned(4))) float f32x4u_t;
typedef __attribute__((ext_vector_type(2))) unsigned int u32x2_t;
typedef __attribute__((ext_vector_type(4))) unsigned int u32x4_t;

typedef const float __attribute__((address_space(1))) gfloat_t;
typedef float __attribute__((address_space(3))) sfloat_t;

// ---------------------------------------------------------------------------
// Prep: W fp32 -> bf16, k-permuted (verified). BN folded to inv/bias.
// ---------------------------------------------------------------------------
__global__ __launch_bounds__(256)
void prep_kernel(const float* __restrict__ pw,
                 const float* __restrict__ g, const float* __restrict__ b,
                 const float* __restrict__ m, const float* __restrict__ v,
                 unsigned short* __restrict__ wper,
                 float* __restrict__ inv, float* __restrict__ bias)
{
    int t = blockIdx.x * 256 + threadIdx.x;
    if (t < CC * CC) {
        int o = t >> 7, cidx = t & 127;
        int kc = cidx >> 5, r = cidx & 31, gg = r >> 3, j = r & 7;
        int c = kc * 32 + gg * 4 + (j & 3) + 16 * (j >> 2);
        __hip_bfloat16 h = __float2bfloat16(pw[o * CC + c]);
        wper[o * CC + cidx] = *reinterpret_cast<unsigned short*>(&h);
    }
    if (t < CC) {
        float iv = g[t] * rsqrtf(v[t] + BN_EPS);
        inv[t] = iv;
        bias[t] = b[t] - m[t] * iv;
    }
}

// ---------------------------------------------------------------------------
// Kernel A (R19): R17's verified DMA-staged depthwise (schedule, mapping,
// halo handling byte-identical — R18's early-return race avoided) + XOR
// bank-swizzle done BOTH-sides-or-neither (rule 21):
//   stage: LDS dest linear (DMA requires); global SOURCE slot-permuted
//          src_slot = slot ^ (row&7)  (self-inverse, stays in [0,24))
//   read:  phys_col = ((col>>2) ^ (rw&7))<<2 | (col&3)
// Kills the stride-96 (== 0 mod 32 banks) 4-way conflict on the 24 b32
// reads — lanes r=0..3 at the same col now hit 4 distinct banks.
// ---------------------------------------------------------------------------
__global__ __launch_bounds__(256, 6)
void dw_kernel(const float* __restrict__ x, const float* __restrict__ kk,
               unsigned short* __restrict__ xn)
{
    __shared__ __align__(16) float tile[2][18 * 96];     // 2 x 6912 B, linear
    const int tid = threadIdx.x;

    const unsigned wg  = blockIdx.x;
    const unsigned bid = (wg & 7u) * 512u + (wg >> 3);   // bijective on [0,4096)
    const int cs = bid & 127;
    const int b  = bid >> 7;

    // storage -> actual channel permutation (blockIdx-derived -> SGPR)
    const int kc = cs >> 5, rr2 = cs & 31, gg = rr2 >> 3, jj = rr2 & 7;
    const int c = kc * 32 + gg * 4 + (jj & 3) + 16 * (jj >> 2);

    const float* plane = x + (size_t)(b * CC + c) * (HH * WW);
    unsigned short* xplane = xn + (size_t)(b * CC + cs) * (HH * WW);

    // block-uniform weights -> scalar loads
    const float* kp = kk + (size_t)(b * CC + c) * 9;
    const float kw0 = kp[0], kw1 = kp[1], kw2 = kp[2];
    const float kw3 = kp[3], kw4 = kp[4], kw5 = kp[5];
    const float kw6 = kp[6], kw7 = kp[7], kw8 = kp[8];

    // staging slots: 432 x 16B; slot s -> (row=s/24, sl=s%24); SOURCE slot
    // is sl ^ (row&7) (XOR of low 3 bits keeps 0..23 in 0..23).
    const int rowA = tid / 24;
    const int slA  = tid % 24;
    const int srcA = slA ^ (rowA & 7);
    const int sB   = tid + 256;
    const int rowB = sB / 24;
    const int slB  = sB % 24;
    const int srcB = slB ^ (rowB & 7);
    const bool hasB = (sB < 432);

    auto STAGE = [&](int t, int buf) {
        int hA = t * 16 - 1 + rowA;
        hA = hA < 0 ? 0 : (hA > HH - 1 ? HH - 1 : hA);
        __builtin_amdgcn_global_load_lds(
            (gfloat_t*)(plane + (size_t)hA * WW + srcA * 4),
            (sfloat_t*)&tile[buf][tid * 4], 16, 0, 0);
        if (hasB) {
            int hB = t * 16 - 1 + rowB;
            hB = hB < 0 ? 0 : (hB > HH - 1 ? HH - 1 : hB);
            __builtin_amdgcn_global_load_lds(
                (gfloat_t*)(plane + (size_t)hB * WW + srcB * 4),
                (sfloat_t*)&tile[buf][sB * 4], 16, 0, 0);
        }
    };

    const int r  = tid >> 4;            // output row in slab, 0..15
    const int cc = (tid & 15) * 6;      // first col, 0..90

    // swizzled LDS read: logical (rw, col) -> physical float index
    auto ldsw = [&](int buf, int rw, int col) -> float {
        const int idx = rw * 96 + ((((col >> 2) ^ (rw & 7)) << 2) | (col & 3));
        return tile[buf][idx];
    };

    auto COMPUTE = [&](int buf, int t) {
        float v[3][8];
        #pragma unroll
        for (int dr = 0; dr < 3; ++dr) {
            const int rw = r + dr;
            const float lv = ldsw(buf, rw, cc == 0 ? 0 : cc - 1);
            v[dr][0] = (cc == 0) ? 0.f : lv;
            #pragma unroll
            for (int i = 0; i < 6; ++i) v[dr][1 + i] = ldsw(buf, rw, cc + i);
            const float rv = ldsw(buf, rw, cc == 90 ? 95 : cc + 6);
            v[dr][7] = (cc == 90) ? 0.f : rv;
        }
        // halo rows (DMA source was clamped): zero them; t literal after unroll
        if (t == 0 && r == 0) {
            #pragma unroll
            for (int i = 0; i < 8; ++i) v[0][i] = 0.f;
        }
        if (t == 5 && r == 15) {
            #pragma unroll
            for (int i = 0; i < 8; ++i) v[2][i] = 0.f;
        }
        unsigned pk[3];
        #pragma unroll
        for (int pr = 0; pr < 3; ++pr) {
            const int j0 = 2 * pr, j1 = j0 + 1;
            float s0 = v[0][j0] * kw0;
            s0 = fmaf(v[0][j0 + 1], kw1, s0);
            s0 = fmaf(v[0][j0 + 2], kw2, s0);
            s0 = fmaf(v[1][j0],     kw3, s0);
            s0 = fmaf(v[1][j0 + 1], kw4, s0);
            s0 = fmaf(v[1][j0 + 2], kw5, s0);
            s0 = fmaf(v[2][j0],     kw6, s0);
            s0 = fmaf(v[2][j0 + 1], kw7, s0);
            s0 = fmaf(v[2][j0 + 2], kw8, s0);
            float s1 = v[0][j1] * kw0;
            s1 = fmaf(v[0][j1 + 1], kw1, s1);
            s1 = fmaf(v[0][j1 + 2], kw2, s1);
            s1 = fmaf(v[1][j1],     kw3, s1);
            s1 = fmaf(v[1][j1 + 1], kw4, s1);
            s1 = fmaf(v[1][j1 + 2], kw5, s1);
            s1 = fmaf(v[2][j1],     kw6, s1);
            s1 = fmaf(v[2][j1 + 1], kw7, s1);
            s1 = fmaf(v[2][j1 + 2], kw8, s1);
            __hip_bfloat16 h0b = __float2bfloat16(s0);
            __hip_bfloat16 h1b = __float2bfloat16(s1);
            pk[pr] = (unsigned)*reinterpret_cast<unsigned short*>(&h0b)
                   | ((unsigned)*reinterpret_cast<unsigned short*>(&h1b) << 16);
        }
        unsigned short* dst = xplane + (size_t)(t * 16 + r) * WW + cc;
        *reinterpret_cast<unsigned*>(dst)     = pk[0];
        *reinterpret_cast<unsigned*>(dst + 2) = pk[1];
        *reinterpret_cast<unsigned*>(dst + 4) = pk[2];
    };

    // ---- pipelined schedule (R17 verbatim) ----
    STAGE(0, 0);
    __syncthreads();            // drains DMA(0)
    STAGE(1, 1);                // flies under COMPUTE(0)

    #pragma unroll
    for (int t = 0; t < 6; ++t) {
        COMPUTE(t & 1, t);
        __syncthreads();        // drains DMA(t+1); LDS-read fence for reuse
        if (t + 2 < 6) STAGE(t + 2, t & 1);
    }
}

// ---------------------------------------------------------------------------
// Kernel B (R13 — verified): pointwise MFMA, 3 h-tiles/block, software-
// pipelined staging, nontemporal stores. Grid 768, XCD-swizzled.
// ---------------------------------------------------------------------------
__global__ __launch_bounds__(256, 3)
void pw_kernel(const unsigned short* __restrict__ xn,
               const unsigned short* __restrict__ wper,
               const float* __restrict__ invp, const float* __restrict__ biasp,
               float* __restrict__ out)
{
    __shared__ __align__(16) unsigned char xnb[128 * 256];
    const int tid = threadIdx.x;

    const unsigned wg  = blockIdx.x;
    const unsigned nid = (wg & 7u) * 96u + (wg >> 3);
    const int tw  = nid % 6u;
    const int thg = (nid / 6u) % 4u;
    const int b   = nid / 24u;
    const int w0  = tw * 16;

    const int lane   = tid & 63;
    const int wv     = tid >> 6;
    const int lo     = lane & 15;
    const int hi     = lane >> 4;
    const int o_base = wv * 32;

    bf16x8_t wfrag[2][4];
    #pragma unroll
    for (int t2 = 0; t2 < 2; ++t2)
        #pragma unroll
        for (int kc = 0; kc < 4; ++kc)
            wfrag[t2][kc] = *reinterpret_cast<const bf16x8_t*>(
                wper + (size_t)(o_base + t2 * 16 + lo) * CC + kc * 32 + hi * 8);

    float iv2[2], bs2[2];
    #pragma unroll
    for (int t2 = 0; t2 < 2; ++t2) {
        iv2[t2] = invp[o_base + t2 * 16 + lo];
        bs2[t2] = biasp[o_base + t2 * 16 + lo];
    }

    const int cs4 = tid >> 3;
    const int py  = tid & 7;
    const unsigned short* src_base =
        xn + (size_t)(b * CC + cs4 * 4) * (HH * WW) + (size_t)py * WW + w0;

    unsigned dLA[4][4], dRA[4][4], dLB[4][4], dRB[4][4];

    auto LOADREGS = [&](int t, unsigned (*dL)[4], unsigned (*dR)[4]) {
        const unsigned short* s0 = src_base + (size_t)((thg * 3 + t) * 8) * WW;
        #pragma unroll
        for (int q = 0; q < 4; ++q) {
            const unsigned short* src = s0 + (size_t)q * (HH * WW);
            u32x4_t L = *(const u32x4_t*)src;
            u32x4_t R = *(const u32x4_t*)(src + 8);
            dL[q][0]=L.x; dL[q][1]=L.y; dL[q][2]=L.z; dL[q][3]=L.w;
            dR[q][0]=R.x; dR[q][1]=R.y; dR[q][2]=R.z; dR[q][3]=R.w;
        }
    };

    auto WRITE_LDS = [&](unsigned (*dL)[4], unsigned (*dR)[4]) {
        #pragma unroll
        for (int o8 = 0; o8 < 2; ++o8) {
            #pragma unroll
            for (int j = 0; j < 4; ++j) {
                const unsigned d0 = o8 ? dR[0][j] : dL[0][j];
                const unsigned d1 = o8 ? dR[1][j] : dL[1][j];
                const unsigned d2 = o8 ? dR[2][j] : dL[2][j];
                const unsigned d3 = o8 ? dR[3][j] : dL[3][j];
                u32x2_t we, wo;
                we.x = __builtin_amdgcn_perm(d1, d0, 0x05040100u);
                we.y = __builtin_amdgcn_perm(d3, d2, 0x05040100u);
                wo.x = __builtin_amdgcn_perm(d1, d0, 0x07060302u);
                wo.y = __builtin_amdgcn_perm(d3, d2, 0x07060302u);
                const int pe = py * 16 + o8 * 8 + 2 * j;
                const int po = pe + 1;
                *reinterpret_cast<u32x2_t*>(&xnb[(unsigned)pe * 256 +
                    (((unsigned)cs4 * 8) ^ (((unsigned)pe & 7u) << 4))]) = we;
                *reinterpret_cast<u32x2_t*>(&xnb[(unsigned)po * 256 +
                    (((unsigned)cs4 * 8) ^ (((unsigned)po & 7u) << 4))]) = wo;
            }
        }
    };

    auto COMPUTE = [&](int t) {
        const int h0 = (thg * 3 + t) * 8;
        f32x4_t acc[8][2];
        #pragma unroll
        for (int pt = 0; pt < 8; ++pt) {
            acc[pt][0] = (f32x4_t){0.f, 0.f, 0.f, 0.f};
            acc[pt][1] = (f32x4_t){0.f, 0.f, 0.f, 0.f};
        }
        #pragma unroll
        for (int pt = 0; pt < 8; ++pt) {
            const unsigned rowbase = (unsigned)(pt * 16 + lo) * 256;
            const unsigned sw = (unsigned)((lo & 7) << 4);
            #pragma unroll
            for (int kc = 0; kc < 4; ++kc) {
                bf16x8_t xfrag = *reinterpret_cast<const bf16x8_t*>(
                    &xnb[rowbase + (((unsigned)(kc * 64 + hi * 16)) ^ sw)]);
                acc[pt][0] = __builtin_amdgcn_mfma_f32_16x16x32_bf16(
                    xfrag, wfrag[0][kc], acc[pt][0], 0, 0, 0);
                acc[pt][1] = __builtin_amdgcn_mfma_f32_16x16x32_bf16(
                    xfrag, wfrag[1][kc], acc[pt][1], 0, 0, 0);
            }
        }
        #pragma unroll
        for (int pt = 0; pt < 8; ++pt) {
            const int hrow = h0 + pt;
            #pragma unroll
            for (int t2 = 0; t2 < 2; ++t2) {
                const int o = o_base + t2 * 16 + lo;
                f32x4_t vv;
                #pragma unroll
                for (int rix = 0; rix < 4; ++rix)
                    vv[rix] = fmaxf(fmaf(acc[pt][t2][rix], iv2[t2], bs2[t2]), 0.f);
                __builtin_nontemporal_store(vv, reinterpret_cast<f32x4_t*>(
                    out + ((size_t)(b * CC + o) * HH + hrow) * WW + w0 + hi * 4));
            }
        }
    };

    LOADREGS(0, dLA, dRA);
    WRITE_LDS(dLA, dRA);
    LOADREGS(1, dLB, dRB);
    __syncthreads();
    COMPUTE(0);
    __syncthreads();
    WRITE_LDS(dLB, dRB);
    LOADREGS(2, dLA, dRA);
    __syncthreads();
    COMPUTE(1);
    __syncthreads();
    WRITE_LDS(dLA, dRA);
    __syncthreads();
    COMPUTE(2);
}

// ---------------------------------------------------------------------------
// Fallback (ws too small): R5 fused kernel.
// ---------------------------------------------------------------------------
__global__ __launch_bounds__(256, 3)
void fused_main(const float* __restrict__ x, const float* __restrict__ kk,
                const unsigned short* __restrict__ wper,
                const float* __restrict__ invp, const float* __restrict__ biasp,
                float* __restrict__ out)
{
    __shared__ __align__(16) unsigned char xnb[128 * 256];
    const int tid = threadIdx.x;
    const unsigned wg  = blockIdx.x;
    const unsigned nid = (wg & 7u) * 288u + (wg >> 3);
    const int bx = nid % 6u;
    const int by = (nid / 6u) % 12u;
    const int bb = nid / 72u;
    const int w0 = bx * 16;
    const int h0 = by * 8;
    {
        const int wq = tid & 3;
        const int cp = tid >> 2;
        const int s  = cp << 1;
        const int kc = s >> 5, rr = s & 31, gg = rr >> 3, jj = rr & 7;
        const int cA = kc * 32 + gg * 4 + (jj & 3) + 16 * (jj >> 2);
        const int gw = w0 + wq * 4;
        const bool l_edge = (gw == 0);
        const bool r_edge = (gw + 4 >= WW);
        const float* planeA = x + (size_t)(bb * CC + cA) * (HH * WW);
        float kwA[9], kwB[9];
        {
            const float* kp = kk + (size_t)(bb * CC + cA) * 9;
            f32x4u_t q0 = *(const f32x4u_t*)(kp + 0);
            f32x4u_t q1 = *(const f32x4u_t*)(kp + 4);
            f32x4u_t q2 = *(const f32x4u_t*)(kp + 8);
            f32x4u_t q3 = *(const f32x4u_t*)(kp + 12);
            float     e16 = kp[16], e17 = kp[17];
            kwA[0]=q0.x; kwA[1]=q0.y; kwA[2]=q0.z; kwA[3]=q0.w;
            kwA[4]=q1.x; kwA[5]=q1.y; kwA[6]=q1.z; kwA[7]=q1.w;
            kwA[8]=q2.x;
            kwB[0]=q2.y; kwB[1]=q2.z; kwB[2]=q2.w;
            kwB[3]=q3.x; kwB[4]=q3.y; kwB[5]=q3.z; kwB[6]=q3.w;
            kwB[7]=e16;  kwB[8]=e17;
        }
        float xd[2][10][6];
        #pragma unroll
        for (int q = 0; q < 2; ++q) {
            const float* plane = planeA + q * (HH * WW);
            #pragma unroll
            for (int r = 0; r < 10; ++r) {
                const int row = h0 - 1 + r;
                const bool valid = (row >= 0) && (row < HH);
                const int rrow = row < 0 ? 0 : (row >= HH ? HH - 1 : row);
                const float* rp = plane + rrow * WW + gw;
                f32x4_t M = *(const f32x4_t*)rp;
                float vl = rp[l_edge ? 0 : -1];
                float vr = rp[r_edge ? 3 : 4];
                xd[q][r][0] = (valid && !l_edge) ? vl : 0.f;
                xd[q][r][1] = valid ? M.x : 0.f;
                xd[q][r][2] = valid ? M.y : 0.f;
                xd[q][r][3] = valid ? M.z : 0.f;
                xd[q][r][4] = valid ? M.w : 0.f;
                xd[q][r][5] = (valid && !r_edge) ? vr : 0.f;
            }
        }
        #pragma unroll
        for (int py = 0; py < 8; ++py) {
            #pragma unroll
            for (int i = 0; i < 4; ++i) {
                float sA = 0.f, sB = 0.f;
                #pragma unroll
                for (int t = 0; t < 3; ++t) {
                    sA = fmaf(xd[0][py + 0][i + t], kwA[t],     sA);
                    sA = fmaf(xd[0][py + 1][i + t], kwA[3 + t], sA);
                    sA = fmaf(xd[0][py + 2][i + t], kwA[6 + t], sA);
                    sB = fmaf(xd[1][py + 0][i + t], kwB[t],     sB);
                    sB = fmaf(xd[1][py + 1][i + t], kwB[3 + t], sB);
                    sB = fmaf(xd[1][py + 2][i + t], kwB[6 + t], sB);
                }
                __hip_bfloat16 hA = __float2bfloat16(sA);
                __hip_bfloat16 hB = __float2bfloat16(sB);
                unsigned pk = (unsigned)*reinterpret_cast<unsigned short*>(&hA)
                            | ((unsigned)*reinterpret_cast<unsigned short*>(&hB) << 16);
                const int p = py * 16 + wq * 4 + i;
                const unsigned boff = ((unsigned)(cp << 2)) ^ (((unsigned)p & 7u) << 4);
                *reinterpret_cast<unsigned*>(&xnb[(unsigned)p * 256 + boff]) = pk;
            }
        }
    }
    __syncthreads();
    {
        const int lane   = tid & 63;
        const int wv     = tid >> 6;
        const int lo     = lane & 15;
        const int hi     = lane >> 4;
        const int o_base = wv * 32;
        bf16x8_t afrag[2][4];
        #pragma unroll
        for (int t2 = 0; t2 < 2; ++t2)
            #pragma unroll
            for (int kc = 0; kc < 4; ++kc)
                afrag[t2][kc] = *reinterpret_cast<const bf16x8_t*>(
                    wper + (size_t)(o_base + t2 * 16 + lo) * CC + kc * 32 + hi * 8);
        f32x4_t acc[8][2];
        #pragma unroll
        for (int pt = 0; pt < 8; ++pt) {
            acc[pt][0] = (f32x4_t){0.f, 0.f, 0.f, 0.f};
            acc[pt][1] = (f32x4_t){0.f, 0.f, 0.f, 0.f};
        }
        #pragma unroll
        for (int pt = 0; pt < 8; ++pt) {
            const unsigned rowbase = (unsigned)(pt * 16 + lo) * 256;
            const unsigned sw = (unsigned)((lo & 7) << 4);
            #pragma unroll
            for (int kc = 0; kc < 4; ++kc) {
                bf16x8_t bfrag = *reinterpret_cast<const bf16x8_t*>(
                    &xnb[rowbase + (((unsigned)(kc * 64 + hi * 16)) ^ sw)]);
                acc[pt][0] = __builtin_amdgcn_mfma_f32_16x16x32_bf16(
                    afrag[0][kc], bfrag, acc[pt][0], 0, 0, 0);
                acc[pt][1] = __builtin_amdgcn_mfma_f32_16x16x32_bf16(
                    afrag[1][kc], bfrag, acc[pt][1], 0, 0, 0);
            }
        }
        float iv[2][4], bs[2][4];
        #pragma unroll
        for (int t2 = 0; t2 < 2; ++t2)
            #pragma unroll
            for (int r = 0; r < 4; ++r) {
                const int o = o_base + t2 * 16 + hi * 4 + r;
                iv[t2][r] = invp[o];
                bs[t2][r] = biasp[o];
            }
        #pragma unroll
        for (int pt = 0; pt < 8; ++pt) {
            const int hrow = h0 + pt;
            #pragma unroll
            for (int t2 = 0; t2 < 2; ++t2) {
                #pragma unroll
                for (int r = 0; r < 4; ++r) {
                    const int o = o_base + t2 * 16 + hi * 4 + r;
                    float val = fmaf(acc[pt][t2][r], iv[t2][r], bs[t2][r]);
                    val = fmaxf(val, 0.f);
                    out[((size_t)(bb * CC + o) * HH + hrow) * WW + w0 + lo] = val;
                }
            }
        }
    }
}

extern "C" void kernel_launch(void* const* d_in, const int* in_sizes, int n_in,
                              void* d_out, int out_size, void* d_ws, size_t ws_size,
                              hipStream_t stream) {
    const float* x   = (const float*)d_in[0];
    const float* kk  = (const float*)d_in[1];
    const float* pwt = (const float*)d_in[2];
    const float* g   = (const float*)d_in[3];
    const float* b   = (const float*)d_in[4];
    const float* m   = (const float*)d_in[5];
    const float* v   = (const float*)d_in[6];
    float* out = (float*)d_out;

    unsigned short* wper = (unsigned short*)d_ws;                 // 32 KB
    float* inv  = (float*)((char*)d_ws + 32768);                  // 512 B
    float* bias = (float*)((char*)d_ws + 32768 + 512);            // 512 B
    unsigned short* xn = (unsigned short*)((char*)d_ws + 36864);  // 75.5 MB
    const size_t need = 36864 + (size_t)BB * CC * HH * WW * 2;

    prep_kernel<<<64, 256, 0, stream>>>(pwt, g, b, m, v, wper, inv, bias);
    if (ws_size >= need) {
        dw_kernel<<<dim3(4096), 256, 0, stream>>>(x, kk, xn);
        pw_kernel<<<dim3(768), 256, 0, stream>>>(xn, wper, inv, bias, out);
    } else {
        fused_main<<<dim3(2304), 256, 0, stream>>>(x, kk, wper, inv, bias, out);
    }
}

// Round 20
// 93.201 us; speedup vs baseline: 1.0229x; 1.0229x over previous
//
#include <hip/hip_runtime.h>
#include <hip/hip_bf16.h>

#define BB 32
#define CC 128
#define HH 96
#define WW 96
#define BN_EPS 1e-5f

typedef __attribute__((ext_vector_type(8))) short bf16x8_t;
typedef __attribute__((ext_vector_type(4))) float f32x4_t;
typedef __attribute__((ext_vector_type(4), aligned(4))) float f32x4u_t;
typedef __attribute__((ext_vector_type(2))) unsigned int u32x2_t;
typedef __attribute__((ext_vector_type(4))) unsigned int u32x4_t;

typedef const float __attribute__((address_space(1))) gfloat_t;
typedef float __attribute__((address_space(3))) sfloat_t;

// ---------------------------------------------------------------------------
// Prep (fallback path only; main path embeds prep in dw).
// ---------------------------------------------------------------------------
__global__ __launch_bounds__(256)
void prep_kernel(const float* __restrict__ pw,
                 const float* __restrict__ g, const float* __restrict__ b,
                 const float* __restrict__ m, const float* __restrict__ v,
                 unsigned short* __restrict__ wper,
                 float* __restrict__ inv, float* __restrict__ bias)
{
    int t = blockIdx.x * 256 + threadIdx.x;
    if (t < CC * CC) {
        int o = t >> 7, cidx = t & 127;
        int kc = cidx >> 5, r = cidx & 31, gg = r >> 3, j = r & 7;
        int c = kc * 32 + gg * 4 + (j & 3) + 16 * (j >> 2);
        __hip_bfloat16 h = __float2bfloat16(pw[o * CC + c]);
        wper[o * CC + cidx] = *reinterpret_cast<unsigned short*>(&h);
    }
    if (t < CC) {
        float iv = g[t] * rsqrtf(v[t] + BN_EPS);
        inv[t] = iv;
        bias[t] = b[t] - m[t] * iv;
    }
}

// ---------------------------------------------------------------------------
// Kernel A (R20): depthwise 3x3 with ZERO barriers — per-WAVE pipelining.
// Seven barrier/chain-coupled structures all plateaued at ~75us with no pipe
// >35% busy; the shared property was coupled progress. Here each wave owns
// one (b,cs) plane end-to-end: per-wave dbuf LDS (10x96 rows), staging via
// global_load_lds (4 DMA instr/slab), counted s_waitcnt vmcnt(4) (in-order
// retirement, m135: the 4 newest outstanding = next-next slab),
// lgkmcnt(0)+sched_barrier fences LDS reads before overwrite (rule 18).
// Both-sides slot-XOR swizzle: src_slot = slot ^ (row&7); read slot ^ (rw&7)
// -> 8 lanes of one col-group across rows hit 8 distinct banks.
// 12 px/lane (8 rows x 8 col-groups of 12), ds_read_b128 x3 + 2 edge b32.
// Grid 1024 x 4 waves = 4096 planes; XCD swizzle; prep embedded (bid<64).
// ---------------------------------------------------------------------------
__global__ __launch_bounds__(256, 5)
void dw_kernel(const float* __restrict__ x, const float* __restrict__ kk,
               const float* __restrict__ pwt,
               const float* __restrict__ bng, const float* __restrict__ bnb,
               const float* __restrict__ bnm, const float* __restrict__ bnv,
               unsigned short* __restrict__ wper,
               float* __restrict__ invp, float* __restrict__ biasp,
               unsigned short* __restrict__ xn)
{
    __shared__ __align__(16) float tile[4][2][960];      // 30720 B
    const int tid  = threadIdx.x;
    const int wv   = tid >> 6;
    const int lane = tid & 63;

    // ---- embedded prep (64 of 1024 blocks; pw launches after dw -> safe) ----
    {
        const int t = blockIdx.x * 256 + tid;
        if (t < CC * CC) {
            int o = t >> 7, cidx = t & 127;
            int kc2 = cidx >> 5, r2 = cidx & 31, g2 = r2 >> 3, j2 = r2 & 7;
            int c2 = kc2 * 32 + g2 * 4 + (j2 & 3) + 16 * (j2 >> 2);
            __hip_bfloat16 h = __float2bfloat16(pwt[o * CC + c2]);
            wper[o * CC + cidx] = *reinterpret_cast<unsigned short*>(&h);
        }
        if (t < CC) {
            float iv = bng[t] * rsqrtf(bnv[t] + BN_EPS);
            invp[t] = iv;
            biasp[t] = bnb[t] - bnm[t] * iv;
        }
    }

    // plane assignment: one wave = one (b,cs) plane
    const unsigned wg  = blockIdx.x;
    const unsigned bid = (wg & 7u) * 128u + (wg >> 3);   // bijective on [0,1024)
    const int p  = (int)bid * 4 + wv;                    // 0..4095
    const int cs = p & 127;
    const int b  = p >> 7;

    // storage -> actual channel permutation
    const int kc = cs >> 5, rr2 = cs & 31, gg = rr2 >> 3, jj = rr2 & 7;
    const int c = kc * 32 + gg * 4 + (jj & 3) + 16 * (jj >> 2);

    const float* plane = x + (size_t)(b * CC + c) * (HH * WW);
    unsigned short* xplane = xn + (size_t)(b * CC + cs) * (HH * WW);

    const float* kp = kk + (size_t)(b * CC + c) * 9;
    const float kw0 = kp[0], kw1 = kp[1], kw2 = kp[2];
    const float kw3 = kp[3], kw4 = kp[4], kw5 = kp[5];
    const float kw6 = kp[6], kw7 = kp[7], kw8 = kp[8];

    // ---- staging: slab t needs x rows t*8-1 .. t*8+8 (10 rows x 24 slots) ----
    auto STAGE = [&](int t, int buf) {
        #pragma unroll
        for (int q = 0; q < 4; ++q) {
            const int slot = q * 64 + lane;
            if (slot < 240) {
                const int row = slot / 24;
                const int sl  = slot % 24;
                const int ssl = sl ^ (row & 7);              // source swizzle
                int xr = t * 8 - 1 + row;
                xr = xr < 0 ? 0 : (xr > HH - 1 ? HH - 1 : xr);
                __builtin_amdgcn_global_load_lds(
                    (gfloat_t*)(plane + (size_t)xr * WW + ssl * 4),
                    (sfloat_t*)&tile[wv][buf][q * 256 + lane * 4], 16, 0, 0);
            }
        }
    };

    // ---- compute: lane = (r = lane>>3, cg = lane&7), 12 px ----
    const int r  = lane >> 3;           // 0..7
    const int cg = lane & 7;            // 0..7
    const int cc = cg * 12;

    auto COMPUTE = [&](int buf, int t) {
        const float* tb = tile[wv][buf];
        float w[3][14];
        #pragma unroll
        for (int dr = 0; dr < 3; ++dr) {
            const int rw  = r + dr;                   // tile row 0..9
            const int key = rw & 7;
            const int base = rw * 96;
            f32x4_t a0 = *(const f32x4_t*)&tb[base + (((3 * cg)     ^ key) << 2)];
            f32x4_t a1 = *(const f32x4_t*)&tb[base + (((3 * cg + 1) ^ key) << 2)];
            f32x4_t a2 = *(const f32x4_t*)&tb[base + (((3 * cg + 2) ^ key) << 2)];
            float lv = tb[base + (((cg == 0 ? 0 : 3 * cg - 1) ^ key) << 2) + 3];
            float rv = tb[base + (((cg == 7 ? 23 : 3 * cg + 3) ^ key) << 2) +
                          (cg == 7 ? 3 : 0)];
            w[dr][0]  = (cg == 0) ? 0.f : lv;
            w[dr][1]  = a0.x; w[dr][2]  = a0.y; w[dr][3]  = a0.z; w[dr][4]  = a0.w;
            w[dr][5]  = a1.x; w[dr][6]  = a1.y; w[dr][7]  = a1.z; w[dr][8]  = a1.w;
            w[dr][9]  = a2.x; w[dr][10] = a2.y; w[dr][11] = a2.z; w[dr][12] = a2.w;
            w[dr][13] = (cg == 7) ? 0.f : rv;
        }
        if (t == 0 && r == 0) {
            #pragma unroll
            for (int i = 0; i < 14; ++i) w[0][i] = 0.f;
        }
        if (t == 11 && r == 7) {
            #pragma unroll
            for (int i = 0; i < 14; ++i) w[2][i] = 0.f;
        }
        unsigned pk[6];
        #pragma unroll
        for (int pr = 0; pr < 6; ++pr) {
            const int j0 = 2 * pr, j1 = j0 + 1;
            float s0 = w[0][j0] * kw0;
            s0 = fmaf(w[0][j0 + 1], kw1, s0);
            s0 = fmaf(w[0][j0 + 2], kw2, s0);
            s0 = fmaf(w[1][j0],     kw3, s0);
            s0 = fmaf(w[1][j0 + 1], kw4, s0);
            s0 = fmaf(w[1][j0 + 2], kw5, s0);
            s0 = fmaf(w[2][j0],     kw6, s0);
            s0 = fmaf(w[2][j0 + 1], kw7, s0);
            s0 = fmaf(w[2][j0 + 2], kw8, s0);
            float s1 = w[0][j1] * kw0;
            s1 = fmaf(w[0][j1 + 1], kw1, s1);
            s1 = fmaf(w[0][j1 + 2], kw2, s1);
            s1 = fmaf(w[1][j1],     kw3, s1);
            s1 = fmaf(w[1][j1 + 1], kw4, s1);
            s1 = fmaf(w[1][j1 + 2], kw5, s1);
            s1 = fmaf(w[2][j1],     kw6, s1);
            s1 = fmaf(w[2][j1 + 1], kw7, s1);
            s1 = fmaf(w[2][j1 + 2], kw8, s1);
            __hip_bfloat16 h0b = __float2bfloat16(s0);
            __hip_bfloat16 h1b = __float2bfloat16(s1);
            pk[pr] = (unsigned)*reinterpret_cast<unsigned short*>(&h0b)
                   | ((unsigned)*reinterpret_cast<unsigned short*>(&h1b) << 16);
        }
        unsigned short* dst = xplane + (size_t)(t * 8 + r) * WW + cc;  // 8B aligned
        u32x2_t v01; v01.x = pk[0]; v01.y = pk[1];
        u32x2_t v23; v23.x = pk[2]; v23.y = pk[3];
        u32x2_t v45; v45.x = pk[4]; v45.y = pk[5];
        *reinterpret_cast<u32x2_t*>(dst)     = v01;
        *reinterpret_cast<u32x2_t*>(dst + 4) = v23;
        *reinterpret_cast<u32x2_t*>(dst + 8) = v45;
    };

    // ---- per-wave pipeline, no barriers ----
    STAGE(0, 0);
    asm volatile("s_waitcnt vmcnt(0)" ::: "memory");
    __builtin_amdgcn_sched_barrier(0);
    STAGE(1, 1);

    #pragma unroll
    for (int t = 0; t < 12; ++t) {
        COMPUTE(t & 1, t);
        asm volatile("s_waitcnt lgkmcnt(0)" ::: "memory");   // LDS reads retired
        __builtin_amdgcn_sched_barrier(0);
        if (t + 2 < 12) {
            STAGE(t + 2, t & 1);                             // overwrite just-read buf
            asm volatile("s_waitcnt vmcnt(4)" ::: "memory"); // slab t+1 landed
        } else {
            asm volatile("s_waitcnt vmcnt(0)" ::: "memory");
        }
        __builtin_amdgcn_sched_barrier(0);
    }
}

// ---------------------------------------------------------------------------
// Kernel B (R13 — verified): pointwise MFMA, 3 h-tiles/block, software-
// pipelined staging, nontemporal stores. Grid 768, XCD-swizzled.
// ---------------------------------------------------------------------------
__global__ __launch_bounds__(256, 3)
void pw_kernel(const unsigned short* __restrict__ xn,
               const unsigned short* __restrict__ wper,
               const float* __restrict__ invp, const float* __restrict__ biasp,
               float* __restrict__ out)
{
    __shared__ __align__(16) unsigned char xnb[128 * 256];
    const int tid = threadIdx.x;

    const unsigned wg  = blockIdx.x;
    const unsigned nid = (wg & 7u) * 96u + (wg >> 3);
    const int tw  = nid % 6u;
    const int thg = (nid / 6u) % 4u;
    const int b   = nid / 24u;
    const int w0  = tw * 16;

    const int lane   = tid & 63;
    const int wv     = tid >> 6;
    const int lo     = lane & 15;
    const int hi     = lane >> 4;
    const int o_base = wv * 32;

    bf16x8_t wfrag[2][4];
    #pragma unroll
    for (int t2 = 0; t2 < 2; ++t2)
        #pragma unroll
        for (int kc = 0; kc < 4; ++kc)
            wfrag[t2][kc] = *reinterpret_cast<const bf16x8_t*>(
                wper + (size_t)(o_base + t2 * 16 + lo) * CC + kc * 32 + hi * 8);

    float iv2[2], bs2[2];
    #pragma unroll
    for (int t2 = 0; t2 < 2; ++t2) {
        iv2[t2] = invp[o_base + t2 * 16 + lo];
        bs2[t2] = biasp[o_base + t2 * 16 + lo];
    }

    const int cs4 = tid >> 3;
    const int py  = tid & 7;
    const unsigned short* src_base =
        xn + (size_t)(b * CC + cs4 * 4) * (HH * WW) + (size_t)py * WW + w0;

    unsigned dLA[4][4], dRA[4][4], dLB[4][4], dRB[4][4];

    auto LOADREGS = [&](int t, unsigned (*dL)[4], unsigned (*dR)[4]) {
        const unsigned short* s0 = src_base + (size_t)((thg * 3 + t) * 8) * WW;
        #pragma unroll
        for (int q = 0; q < 4; ++q) {
            const unsigned short* src = s0 + (size_t)q * (HH * WW);
            u32x4_t L = *(const u32x4_t*)src;
            u32x4_t R = *(const u32x4_t*)(src + 8);
            dL[q][0]=L.x; dL[q][1]=L.y; dL[q][2]=L.z; dL[q][3]=L.w;
            dR[q][0]=R.x; dR[q][1]=R.y; dR[q][2]=R.z; dR[q][3]=R.w;
        }
    };

    auto WRITE_LDS = [&](unsigned (*dL)[4], unsigned (*dR)[4]) {
        #pragma unroll
        for (int o8 = 0; o8 < 2; ++o8) {
            #pragma unroll
            for (int j = 0; j < 4; ++j) {
                const unsigned d0 = o8 ? dR[0][j] : dL[0][j];
                const unsigned d1 = o8 ? dR[1][j] : dL[1][j];
                const unsigned d2 = o8 ? dR[2][j] : dL[2][j];
                const unsigned d3 = o8 ? dR[3][j] : dL[3][j];
                u32x2_t we, wo;
                we.x = __builtin_amdgcn_perm(d1, d0, 0x05040100u);
                we.y = __builtin_amdgcn_perm(d3, d2, 0x05040100u);
                wo.x = __builtin_amdgcn_perm(d1, d0, 0x07060302u);
                wo.y = __builtin_amdgcn_perm(d3, d2, 0x07060302u);
                const int pe = py * 16 + o8 * 8 + 2 * j;
                const int po = pe + 1;
                *reinterpret_cast<u32x2_t*>(&xnb[(unsigned)pe * 256 +
                    (((unsigned)cs4 * 8) ^ (((unsigned)pe & 7u) << 4))]) = we;
                *reinterpret_cast<u32x2_t*>(&xnb[(unsigned)po * 256 +
                    (((unsigned)cs4 * 8) ^ (((unsigned)po & 7u) << 4))]) = wo;
            }
        }
    };

    auto COMPUTE = [&](int t) {
        const int h0 = (thg * 3 + t) * 8;
        f32x4_t acc[8][2];
        #pragma unroll
        for (int pt = 0; pt < 8; ++pt) {
            acc[pt][0] = (f32x4_t){0.f, 0.f, 0.f, 0.f};
            acc[pt][1] = (f32x4_t){0.f, 0.f, 0.f, 0.f};
        }
        #pragma unroll
        for (int pt = 0; pt < 8; ++pt) {
            const unsigned rowbase = (unsigned)(pt * 16 + lo) * 256;
            const unsigned sw = (unsigned)((lo & 7) << 4);
            #pragma unroll
            for (int kc = 0; kc < 4; ++kc) {
                bf16x8_t xfrag = *reinterpret_cast<const bf16x8_t*>(
                    &xnb[rowbase + (((unsigned)(kc * 64 + hi * 16)) ^ sw)]);
                acc[pt][0] = __builtin_amdgcn_mfma_f32_16x16x32_bf16(
                    xfrag, wfrag[0][kc], acc[pt][0], 0, 0, 0);
                acc[pt][1] = __builtin_amdgcn_mfma_f32_16x16x32_bf16(
                    xfrag, wfrag[1][kc], acc[pt][1], 0, 0, 0);
            }
        }
        #pragma unroll
        for (int pt = 0; pt < 8; ++pt) {
            const int hrow = h0 + pt;
            #pragma unroll
            for (int t2 = 0; t2 < 2; ++t2) {
                const int o = o_base + t2 * 16 + lo;
                f32x4_t vv;
                #pragma unroll
                for (int rix = 0; rix < 4; ++rix)
                    vv[rix] = fmaxf(fmaf(acc[pt][t2][rix], iv2[t2], bs2[t2]), 0.f);
                __builtin_nontemporal_store(vv, reinterpret_cast<f32x4_t*>(
                    out + ((size_t)(b * CC + o) * HH + hrow) * WW + w0 + hi * 4));
            }
        }
    };

    LOADREGS(0, dLA, dRA);
    WRITE_LDS(dLA, dRA);
    LOADREGS(1, dLB, dRB);
    __syncthreads();
    COMPUTE(0);
    __syncthreads();
    WRITE_LDS(dLB, dRB);
    LOADREGS(2, dLA, dRA);
    __syncthreads();
    COMPUTE(1);
    __syncthreads();
    WRITE_LDS(dLA, dRA);
    __syncthreads();
    COMPUTE(2);
}

// ---------------------------------------------------------------------------
// Fallback (ws too small): R5 fused kernel.
// ---------------------------------------------------------------------------
__global__ __launch_bounds__(256, 3)
void fused_main(const float* __restrict__ x, const float* __restrict__ kk,
                const unsigned short* __restrict__ wper,
                const float* __restrict__ invp, const float* __restrict__ biasp,
                float* __restrict__ out)
{
    __shared__ __align__(16) unsigned char xnb[128 * 256];
    const int tid = threadIdx.x;
    const unsigned wg  = blockIdx.x;
    const unsigned nid = (wg & 7u) * 288u + (wg >> 3);
    const int bx = nid % 6u;
    const int by = (nid / 6u) % 12u;
    const int bb = nid / 72u;
    const int w0 = bx * 16;
    const int h0 = by * 8;
    {
        const int wq = tid & 3;
        const int cp = tid >> 2;
        const int s  = cp << 1;
        const int kc = s >> 5, rr = s & 31, gg = rr >> 3, jj = rr & 7;
        const int cA = kc * 32 + gg * 4 + (jj & 3) + 16 * (jj >> 2);
        const int gw = w0 + wq * 4;
        const bool l_edge = (gw == 0);
        const bool r_edge = (gw + 4 >= WW);
        const float* planeA = x + (size_t)(bb * CC + cA) * (HH * WW);
        float kwA[9], kwB[9];
        {
            const float* kp = kk + (size_t)(bb * CC + cA) * 9;
            f32x4u_t q0 = *(const f32x4u_t*)(kp + 0);
            f32x4u_t q1 = *(const f32x4u_t*)(kp + 4);
            f32x4u_t q2 = *(const f32x4u_t*)(kp + 8);
            f32x4u_t q3 = *(const f32x4u_t*)(kp + 12);
            float     e16 = kp[16], e17 = kp[17];
            kwA[0]=q0.x; kwA[1]=q0.y; kwA[2]=q0.z; kwA[3]=q0.w;
            kwA[4]=q1.x; kwA[5]=q1.y; kwA[6]=q1.z; kwA[7]=q1.w;
            kwA[8]=q2.x;
            kwB[0]=q2.y; kwB[1]=q2.z; kwB[2]=q2.w;
            kwB[3]=q3.x; kwB[4]=q3.y; kwB[5]=q3.z; kwB[6]=q3.w;
            kwB[7]=e16;  kwB[8]=e17;
        }
        float xd[2][10][6];
        #pragma unroll
        for (int q = 0; q < 2; ++q) {
            const float* plane = planeA + q * (HH * WW);
            #pragma unroll
            for (int r = 0; r < 10; ++r) {
                const int row = h0 - 1 + r;
                const bool valid = (row >= 0) && (row < HH);
                const int rrow = row < 0 ? 0 : (row >= HH ? HH - 1 : row);
                const float* rp = plane + rrow * WW + gw;
                f32x4_t M = *(const f32x4_t*)rp;
                float vl = rp[l_edge ? 0 : -1];
                float vr = rp[r_edge ? 3 : 4];
                xd[q][r][0] = (valid && !l_edge) ? vl : 0.f;
                xd[q][r][1] = valid ? M.x : 0.f;
                xd[q][r][2] = valid ? M.y : 0.f;
                xd[q][r][3] = valid ? M.z : 0.f;
                xd[q][r][4] = valid ? M.w : 0.f;
                xd[q][r][5] = (valid && !r_edge) ? vr : 0.f;
            }
        }
        #pragma unroll
        for (int py = 0; py < 8; ++py) {
            #pragma unroll
            for (int i = 0; i < 4; ++i) {
                float sA = 0.f, sB = 0.f;
                #pragma unroll
                for (int t = 0; t < 3; ++t) {
                    sA = fmaf(xd[0][py + 0][i + t], kwA[t],     sA);
                    sA = fmaf(xd[0][py + 1][i + t], kwA[3 + t], sA);
                    sA = fmaf(xd[0][py + 2][i + t], kwA[6 + t], sA);
                    sB = fmaf(xd[1][py + 0][i + t], kwB[t],     sB);
                    sB = fmaf(xd[1][py + 1][i + t], kwB[3 + t], sB);
                    sB = fmaf(xd[1][py + 2][i + t], kwB[6 + t], sB);
                }
                __hip_bfloat16 hA = __float2bfloat16(sA);
                __hip_bfloat16 hB = __float2bfloat16(sB);
                unsigned pk = (unsigned)*reinterpret_cast<unsigned short*>(&hA)
                            | ((unsigned)*reinterpret_cast<unsigned short*>(&hB) << 16);
                const int p = py * 16 + wq * 4 + i;
                const unsigned boff = ((unsigned)(cp << 2)) ^ (((unsigned)p & 7u) << 4);
                *reinterpret_cast<unsigned*>(&xnb[(unsigned)p * 256 + boff]) = pk;
            }
        }
    }
    __syncthreads();
    {
        const int lane   = tid & 63;
        const int wv     = tid >> 6;
        const int lo     = lane & 15;
        const int hi     = lane >> 4;
        const int o_base = wv * 32;
        bf16x8_t afrag[2][4];
        #pragma unroll
        for (int t2 = 0; t2 < 2; ++t2)
            #pragma unroll
            for (int kc = 0; kc < 4; ++kc)
                afrag[t2][kc] = *reinterpret_cast<const bf16x8_t*>(
                    wper + (size_t)(o_base + t2 * 16 + lo) * CC + kc * 32 + hi * 8);
        f32x4_t acc[8][2];
        #pragma unroll
        for (int pt = 0; pt < 8; ++pt) {
            acc[pt][0] = (f32x4_t){0.f, 0.f, 0.f, 0.f};
            acc[pt][1] = (f32x4_t){0.f, 0.f, 0.f, 0.f};
        }
        #pragma unroll
        for (int pt = 0; pt < 8; ++pt) {
            const unsigned rowbase = (unsigned)(pt * 16 + lo) * 256;
            const unsigned sw = (unsigned)((lo & 7) << 4);
            #pragma unroll
            for (int kc = 0; kc < 4; ++kc) {
                bf16x8_t bfrag = *reinterpret_cast<const bf16x8_t*>(
                    &xnb[rowbase + (((unsigned)(kc * 64 + hi * 16)) ^ sw)]);
                acc[pt][0] = __builtin_amdgcn_mfma_f32_16x16x32_bf16(
                    afrag[0][kc], bfrag, acc[pt][0], 0, 0, 0);
                acc[pt][1] = __builtin_amdgcn_mfma_f32_16x16x32_bf16(
                    afrag[1][kc], bfrag, acc[pt][1], 0, 0, 0);
            }
        }
        float iv[2][4], bs[2][4];
        #pragma unroll
        for (int t2 = 0; t2 < 2; ++t2)
            #pragma unroll
            for (int r = 0; r < 4; ++r) {
                const int o = o_base + t2 * 16 + hi * 4 + r;
                iv[t2][r] = invp[o];
                bs[t2][r] = biasp[o];
            }
        #pragma unroll
        for (int pt = 0; pt < 8; ++pt) {
            const int hrow = h0 + pt;
            #pragma unroll
            for (int t2 = 0; t2 < 2; ++t2) {
                #pragma unroll
                for (int r = 0; r < 4; ++r) {
                    const int o = o_base + t2 * 16 + hi * 4 + r;
                    float val = fmaf(acc[pt][t2][r], iv[t2][r], bs[t2][r]);
                    val = fmaxf(val, 0.f);
                    out[((size_t)(bb * CC + o) * HH + hrow) * WW + w0 + lo] = val;
                }
            }
        }
    }
}

extern "C" void kernel_launch(void* const* d_in, const int* in_sizes, int n_in,
                              void* d_out, int out_size, void* d_ws, size_t ws_size,
                              hipStream_t stream) {
    const float* x   = (const float*)d_in[0];
    const float* kk  = (const float*)d_in[1];
    const float* pwt = (const float*)d_in[2];
    const float* g   = (const float*)d_in[3];
    const float* b   = (const float*)d_in[4];
    const float* m   = (const float*)d_in[5];
    const float* v   = (const float*)d_in[6];
    float* out = (float*)d_out;

    unsigned short* wper = (unsigned short*)d_ws;                 // 32 KB
    float* inv  = (float*)((char*)d_ws + 32768);                  // 512 B
    float* bias = (float*)((char*)d_ws + 32768 + 512);            // 512 B
    unsigned short* xn = (unsigned short*)((char*)d_ws + 36864);  // 75.5 MB
    const size_t need = 36864 + (size_t)BB * CC * HH * WW * 2;

    if (ws_size >= need) {
        dw_kernel<<<dim3(1024), 256, 0, stream>>>(x, kk, pwt, g, b, m, v,
                                                  wper, inv, bias, xn);
        pw_kernel<<<dim3(768), 256, 0, stream>>>(xn, wper, inv, bias, out);
    } else {
        prep_kernel<<<64, 256, 0, stream>>>(pwt, g, b, m, v, wper, inv, bias);
        fused_main<<<dim3(2304), 256, 0, stream>>>(x, kk, wper, inv, bias, out);
    }
}

// Round 21
// 93.144 us; speedup vs baseline: 1.0235x; 1.0006x over previous
//
#include <hip/hip_runtime.h>
#include <hip/hip_bf16.h>

#define BB 32
#define CC 128
#define HH 96
#define WW 96
#define BN_EPS 1e-5f

typedef __attribute__((ext_vector_type(8))) short bf16x8_t;
typedef __attribute__((ext_vector_type(4))) float f32x4_t;
typedef __attribute__((ext_vector_type(4), aligned(4))) float f32x4u_t;
typedef __attribute__((ext_vector_type(2))) unsigned int u32x2_t;
typedef __attribute__((ext_vector_type(4))) unsigned int u32x4_t;

typedef const float __attribute__((address_space(1))) gfloat_t;
typedef float __attribute__((address_space(3))) sfloat_t;

// ---------------------------------------------------------------------------
// Prep (fallback path only; main path embeds prep in dw).
// ---------------------------------------------------------------------------
__global__ __launch_bounds__(256)
void prep_kernel(const float* __restrict__ pw,
                 const float* __restrict__ g, const float* __restrict__ b,
                 const float* __restrict__ m, const float* __restrict__ v,
                 unsigned short* __restrict__ wper,
                 float* __restrict__ inv, float* __restrict__ bias)
{
    int t = blockIdx.x * 256 + threadIdx.x;
    if (t < CC * CC) {
        int o = t >> 7, cidx = t & 127;
        int kc = cidx >> 5, r = cidx & 31, gg = r >> 3, j = r & 7;
        int c = kc * 32 + gg * 4 + (j & 3) + 16 * (j >> 2);
        __hip_bfloat16 h = __float2bfloat16(pw[o * CC + c]);
        wper[o * CC + cidx] = *reinterpret_cast<unsigned short*>(&h);
    }
    if (t < CC) {
        float iv = g[t] * rsqrtf(v[t] + BN_EPS);
        inv[t] = iv;
        bias[t] = b[t] - m[t] * iv;
    }
}

// ---------------------------------------------------------------------------
// Kernel A (R21 = R20 + one wait fix): barrier-free per-wave pipelined dw.
// R20's vmcnt(4) after STAGE(t+2) also drained COMPUTE's 3 xn stores
// (vmcnt counts stores; in-order retirement, m135). vmcnt(7) with 11
// outstanding releases exactly the 4 oldest = STAGE(t+1)'s loads — the
// only ops COMPUTE(t+1) depends on — without stalling on the store stream.
// Everything else byte-identical to the clean-passing R20.
// ---------------------------------------------------------------------------
__global__ __launch_bounds__(256, 5)
void dw_kernel(const float* __restrict__ x, const float* __restrict__ kk,
               const float* __restrict__ pwt,
               const float* __restrict__ bng, const float* __restrict__ bnb,
               const float* __restrict__ bnm, const float* __restrict__ bnv,
               unsigned short* __restrict__ wper,
               float* __restrict__ invp, float* __restrict__ biasp,
               unsigned short* __restrict__ xn)
{
    __shared__ __align__(16) float tile[4][2][960];      // 30720 B
    const int tid  = threadIdx.x;
    const int wv   = tid >> 6;
    const int lane = tid & 63;

    // ---- embedded prep (64 of 1024 blocks; pw launches after dw -> safe) ----
    {
        const int t = blockIdx.x * 256 + tid;
        if (t < CC * CC) {
            int o = t >> 7, cidx = t & 127;
            int kc2 = cidx >> 5, r2 = cidx & 31, g2 = r2 >> 3, j2 = r2 & 7;
            int c2 = kc2 * 32 + g2 * 4 + (j2 & 3) + 16 * (j2 >> 2);
            __hip_bfloat16 h = __float2bfloat16(pwt[o * CC + c2]);
            wper[o * CC + cidx] = *reinterpret_cast<unsigned short*>(&h);
        }
        if (t < CC) {
            float iv = bng[t] * rsqrtf(bnv[t] + BN_EPS);
            invp[t] = iv;
            biasp[t] = bnb[t] - bnm[t] * iv;
        }
    }

    // plane assignment: one wave = one (b,cs) plane
    const unsigned wg  = blockIdx.x;
    const unsigned bid = (wg & 7u) * 128u + (wg >> 3);   // bijective on [0,1024)
    const int p  = (int)bid * 4 + wv;                    // 0..4095
    const int cs = p & 127;
    const int b  = p >> 7;

    // storage -> actual channel permutation
    const int kc = cs >> 5, rr2 = cs & 31, gg = rr2 >> 3, jj = rr2 & 7;
    const int c = kc * 32 + gg * 4 + (jj & 3) + 16 * (jj >> 2);

    const float* plane = x + (size_t)(b * CC + c) * (HH * WW);
    unsigned short* xplane = xn + (size_t)(b * CC + cs) * (HH * WW);

    const float* kp = kk + (size_t)(b * CC + c) * 9;
    const float kw0 = kp[0], kw1 = kp[1], kw2 = kp[2];
    const float kw3 = kp[3], kw4 = kp[4], kw5 = kp[5];
    const float kw6 = kp[6], kw7 = kp[7], kw8 = kp[8];

    // ---- staging: slab t needs x rows t*8-1 .. t*8+8 (10 rows x 24 slots) ----
    auto STAGE = [&](int t, int buf) {
        #pragma unroll
        for (int q = 0; q < 4; ++q) {
            const int slot = q * 64 + lane;
            if (slot < 240) {
                const int row = slot / 24;
                const int sl  = slot % 24;
                const int ssl = sl ^ (row & 7);              // source swizzle
                int xr = t * 8 - 1 + row;
                xr = xr < 0 ? 0 : (xr > HH - 1 ? HH - 1 : xr);
                __builtin_amdgcn_global_load_lds(
                    (gfloat_t*)(plane + (size_t)xr * WW + ssl * 4),
                    (sfloat_t*)&tile[wv][buf][q * 256 + lane * 4], 16, 0, 0);
            }
        }
    };

    // ---- compute: lane = (r = lane>>3, cg = lane&7), 12 px ----
    const int r  = lane >> 3;           // 0..7
    const int cg = lane & 7;            // 0..7
    const int cc = cg * 12;

    auto COMPUTE = [&](int buf, int t) {
        const float* tb = tile[wv][buf];
        float w[3][14];
        #pragma unroll
        for (int dr = 0; dr < 3; ++dr) {
            const int rw  = r + dr;                   // tile row 0..9
            const int key = rw & 7;
            const int base = rw * 96;
            f32x4_t a0 = *(const f32x4_t*)&tb[base + (((3 * cg)     ^ key) << 2)];
            f32x4_t a1 = *(const f32x4_t*)&tb[base + (((3 * cg + 1) ^ key) << 2)];
            f32x4_t a2 = *(const f32x4_t*)&tb[base + (((3 * cg + 2) ^ key) << 2)];
            float lv = tb[base + (((cg == 0 ? 0 : 3 * cg - 1) ^ key) << 2) + 3];
            float rv = tb[base + (((cg == 7 ? 23 : 3 * cg + 3) ^ key) << 2) +
                          (cg == 7 ? 3 : 0)];
            w[dr][0]  = (cg == 0) ? 0.f : lv;
            w[dr][1]  = a0.x; w[dr][2]  = a0.y; w[dr][3]  = a0.z; w[dr][4]  = a0.w;
            w[dr][5]  = a1.x; w[dr][6]  = a1.y; w[dr][7]  = a1.z; w[dr][8]  = a1.w;
            w[dr][9]  = a2.x; w[dr][10] = a2.y; w[dr][11] = a2.z; w[dr][12] = a2.w;
            w[dr][13] = (cg == 7) ? 0.f : rv;
        }
        if (t == 0 && r == 0) {
            #pragma unroll
            for (int i = 0; i < 14; ++i) w[0][i] = 0.f;
        }
        if (t == 11 && r == 7) {
            #pragma unroll
            for (int i = 0; i < 14; ++i) w[2][i] = 0.f;
        }
        unsigned pk[6];
        #pragma unroll
        for (int pr = 0; pr < 6; ++pr) {
            const int j0 = 2 * pr, j1 = j0 + 1;
            float s0 = w[0][j0] * kw0;
            s0 = fmaf(w[0][j0 + 1], kw1, s0);
            s0 = fmaf(w[0][j0 + 2], kw2, s0);
            s0 = fmaf(w[1][j0],     kw3, s0);
            s0 = fmaf(w[1][j0 + 1], kw4, s0);
            s0 = fmaf(w[1][j0 + 2], kw5, s0);
            s0 = fmaf(w[2][j0],     kw6, s0);
            s0 = fmaf(w[2][j0 + 1], kw7, s0);
            s0 = fmaf(w[2][j0 + 2], kw8, s0);
            float s1 = w[0][j1] * kw0;
            s1 = fmaf(w[0][j1 + 1], kw1, s1);
            s1 = fmaf(w[0][j1 + 2], kw2, s1);
            s1 = fmaf(w[1][j1],     kw3, s1);
            s1 = fmaf(w[1][j1 + 1], kw4, s1);
            s1 = fmaf(w[1][j1 + 2], kw5, s1);
            s1 = fmaf(w[2][j1],     kw6, s1);
            s1 = fmaf(w[2][j1 + 1], kw7, s1);
            s1 = fmaf(w[2][j1 + 2], kw8, s1);
            __hip_bfloat16 h0b = __float2bfloat16(s0);
            __hip_bfloat16 h1b = __float2bfloat16(s1);
            pk[pr] = (unsigned)*reinterpret_cast<unsigned short*>(&h0b)
                   | ((unsigned)*reinterpret_cast<unsigned short*>(&h1b) << 16);
        }
        unsigned short* dst = xplane + (size_t)(t * 8 + r) * WW + cc;  // 8B aligned
        u32x2_t v01; v01.x = pk[0]; v01.y = pk[1];
        u32x2_t v23; v23.x = pk[2]; v23.y = pk[3];
        u32x2_t v45; v45.x = pk[4]; v45.y = pk[5];
        *reinterpret_cast<u32x2_t*>(dst)     = v01;
        *reinterpret_cast<u32x2_t*>(dst + 4) = v23;
        *reinterpret_cast<u32x2_t*>(dst + 8) = v45;
    };

    // ---- per-wave pipeline, no barriers ----
    STAGE(0, 0);
    asm volatile("s_waitcnt vmcnt(0)" ::: "memory");
    __builtin_amdgcn_sched_barrier(0);
    STAGE(1, 1);

    #pragma unroll
    for (int t = 0; t < 12; ++t) {
        COMPUTE(t & 1, t);
        asm volatile("s_waitcnt lgkmcnt(0)" ::: "memory");   // LDS reads retired
        __builtin_amdgcn_sched_barrier(0);
        if (t + 2 < 12) {
            STAGE(t + 2, t & 1);                             // overwrite just-read buf
            // 11 outstanding (4 loads t+1, 3 stores, 4 loads t+2); wait the
            // 4 oldest only = STAGE(t+1)'s loads (in-order retirement, m135).
            asm volatile("s_waitcnt vmcnt(7)" ::: "memory");
        } else {
            asm volatile("s_waitcnt vmcnt(0)" ::: "memory");
        }
        __builtin_amdgcn_sched_barrier(0);
    }
}

// ---------------------------------------------------------------------------
// Kernel B (R13 — verified): pointwise MFMA, 3 h-tiles/block, software-
// pipelined staging, nontemporal stores. Grid 768, XCD-swizzled.
// ---------------------------------------------------------------------------
__global__ __launch_bounds__(256, 3)
void pw_kernel(const unsigned short* __restrict__ xn,
               const unsigned short* __restrict__ wper,
               const float* __restrict__ invp, const float* __restrict__ biasp,
               float* __restrict__ out)
{
    __shared__ __align__(16) unsigned char xnb[128 * 256];
    const int tid = threadIdx.x;

    const unsigned wg  = blockIdx.x;
    const unsigned nid = (wg & 7u) * 96u + (wg >> 3);
    const int tw  = nid % 6u;
    const int thg = (nid / 6u) % 4u;
    const int b   = nid / 24u;
    const int w0  = tw * 16;

    const int lane   = tid & 63;
    const int wv     = tid >> 6;
    const int lo     = lane & 15;
    const int hi     = lane >> 4;
    const int o_base = wv * 32;

    bf16x8_t wfrag[2][4];
    #pragma unroll
    for (int t2 = 0; t2 < 2; ++t2)
        #pragma unroll
        for (int kc = 0; kc < 4; ++kc)
            wfrag[t2][kc] = *reinterpret_cast<const bf16x8_t*>(
                wper + (size_t)(o_base + t2 * 16 + lo) * CC + kc * 32 + hi * 8);

    float iv2[2], bs2[2];
    #pragma unroll
    for (int t2 = 0; t2 < 2; ++t2) {
        iv2[t2] = invp[o_base + t2 * 16 + lo];
        bs2[t2] = biasp[o_base + t2 * 16 + lo];
    }

    const int cs4 = tid >> 3;
    const int py  = tid & 7;
    const unsigned short* src_base =
        xn + (size_t)(b * CC + cs4 * 4) * (HH * WW) + (size_t)py * WW + w0;

    unsigned dLA[4][4], dRA[4][4], dLB[4][4], dRB[4][4];

    auto LOADREGS = [&](int t, unsigned (*dL)[4], unsigned (*dR)[4]) {
        const unsigned short* s0 = src_base + (size_t)((thg * 3 + t) * 8) * WW;
        #pragma unroll
        for (int q = 0; q < 4; ++q) {
            const unsigned short* src = s0 + (size_t)q * (HH * WW);
            u32x4_t L = *(const u32x4_t*)src;
            u32x4_t R = *(const u32x4_t*)(src + 8);
            dL[q][0]=L.x; dL[q][1]=L.y; dL[q][2]=L.z; dL[q][3]=L.w;
            dR[q][0]=R.x; dR[q][1]=R.y; dR[q][2]=R.z; dR[q][3]=R.w;
        }
    };

    auto WRITE_LDS = [&](unsigned (*dL)[4], unsigned (*dR)[4]) {
        #pragma unroll
        for (int o8 = 0; o8 < 2; ++o8) {
            #pragma unroll
            for (int j = 0; j < 4; ++j) {
                const unsigned d0 = o8 ? dR[0][j] : dL[0][j];
                const unsigned d1 = o8 ? dR[1][j] : dL[1][j];
                const unsigned d2 = o8 ? dR[2][j] : dL[2][j];
                const unsigned d3 = o8 ? dR[3][j] : dL[3][j];
                u32x2_t we, wo;
                we.x = __builtin_amdgcn_perm(d1, d0, 0x05040100u);
                we.y = __builtin_amdgcn_perm(d3, d2, 0x05040100u);
                wo.x = __builtin_amdgcn_perm(d1, d0, 0x07060302u);
                wo.y = __builtin_amdgcn_perm(d3, d2, 0x07060302u);
                const int pe = py * 16 + o8 * 8 + 2 * j;
                const int po = pe + 1;
                *reinterpret_cast<u32x2_t*>(&xnb[(unsigned)pe * 256 +
                    (((unsigned)cs4 * 8) ^ (((unsigned)pe & 7u) << 4))]) = we;
                *reinterpret_cast<u32x2_t*>(&xnb[(unsigned)po * 256 +
                    (((unsigned)cs4 * 8) ^ (((unsigned)po & 7u) << 4))]) = wo;
            }
        }
    };

    auto COMPUTE = [&](int t) {
        const int h0 = (thg * 3 + t) * 8;
        f32x4_t acc[8][2];
        #pragma unroll
        for (int pt = 0; pt < 8; ++pt) {
            acc[pt][0] = (f32x4_t){0.f, 0.f, 0.f, 0.f};
            acc[pt][1] = (f32x4_t){0.f, 0.f, 0.f, 0.f};
        }
        #pragma unroll
        for (int pt = 0; pt < 8; ++pt) {
            const unsigned rowbase = (unsigned)(pt * 16 + lo) * 256;
            const unsigned sw = (unsigned)((lo & 7) << 4);
            #pragma unroll
            for (int kc = 0; kc < 4; ++kc) {
                bf16x8_t xfrag = *reinterpret_cast<const bf16x8_t*>(
                    &xnb[rowbase + (((unsigned)(kc * 64 + hi * 16)) ^ sw)]);
                acc[pt][0] = __builtin_amdgcn_mfma_f32_16x16x32_bf16(
                    xfrag, wfrag[0][kc], acc[pt][0], 0, 0, 0);
                acc[pt][1] = __builtin_amdgcn_mfma_f32_16x16x32_bf16(
                    xfrag, wfrag[1][kc], acc[pt][1], 0, 0, 0);
            }
        }
        #pragma unroll
        for (int pt = 0; pt < 8; ++pt) {
            const int hrow = h0 + pt;
            #pragma unroll
            for (int t2 = 0; t2 < 2; ++t2) {
                const int o = o_base + t2 * 16 + lo;
                f32x4_t vv;
                #pragma unroll
                for (int rix = 0; rix < 4; ++rix)
                    vv[rix] = fmaxf(fmaf(acc[pt][t2][rix], iv2[t2], bs2[t2]), 0.f);
                __builtin_nontemporal_store(vv, reinterpret_cast<f32x4_t*>(
                    out + ((size_t)(b * CC + o) * HH + hrow) * WW + w0 + hi * 4));
            }
        }
    };

    LOADREGS(0, dLA, dRA);
    WRITE_LDS(dLA, dRA);
    LOADREGS(1, dLB, dRB);
    __syncthreads();
    COMPUTE(0);
    __syncthreads();
    WRITE_LDS(dLB, dRB);
    LOADREGS(2, dLA, dRA);
    __syncthreads();
    COMPUTE(1);
    __syncthreads();
    WRITE_LDS(dLA, dRA);
    __syncthreads();
    COMPUTE(2);
}

// ---------------------------------------------------------------------------
// Fallback (ws too small): R5 fused kernel.
// ---------------------------------------------------------------------------
__global__ __launch_bounds__(256, 3)
void fused_main(const float* __restrict__ x, const float* __restrict__ kk,
                const unsigned short* __restrict__ wper,
                const float* __restrict__ invp, const float* __restrict__ biasp,
                float* __restrict__ out)
{
    __shared__ __align__(16) unsigned char xnb[128 * 256];
    const int tid = threadIdx.x;
    const unsigned wg  = blockIdx.x;
    const unsigned nid = (wg & 7u) * 288u + (wg >> 3);
    const int bx = nid % 6u;
    const int by = (nid / 6u) % 12u;
    const int bb = nid / 72u;
    const int w0 = bx * 16;
    const int h0 = by * 8;
    {
        const int wq = tid & 3;
        const int cp = tid >> 2;
        const int s  = cp << 1;
        const int kc = s >> 5, rr = s & 31, gg = rr >> 3, jj = rr & 7;
        const int cA = kc * 32 + gg * 4 + (jj & 3) + 16 * (jj >> 2);
        const int gw = w0 + wq * 4;
        const bool l_edge = (gw == 0);
        const bool r_edge = (gw + 4 >= WW);
        const float* planeA = x + (size_t)(bb * CC + cA) * (HH * WW);
        float kwA[9], kwB[9];
        {
            const float* kp = kk + (size_t)(bb * CC + cA) * 9;
            f32x4u_t q0 = *(const f32x4u_t*)(kp + 0);
            f32x4u_t q1 = *(const f32x4u_t*)(kp + 4);
            f32x4u_t q2 = *(const f32x4u_t*)(kp + 8);
            f32x4u_t q3 = *(const f32x4u_t*)(kp + 12);
            float     e16 = kp[16], e17 = kp[17];
            kwA[0]=q0.x; kwA[1]=q0.y; kwA[2]=q0.z; kwA[3]=q0.w;
            kwA[4]=q1.x; kwA[5]=q1.y; kwA[6]=q1.z; kwA[7]=q1.w;
            kwA[8]=q2.x;
            kwB[0]=q2.y; kwB[1]=q2.z; kwB[2]=q2.w;
            kwB[3]=q3.x; kwB[4]=q3.y; kwB[5]=q3.z; kwB[6]=q3.w;
            kwB[7]=e16;  kwB[8]=e17;
        }
        float xd[2][10][6];
        #pragma unroll
        for (int q = 0; q < 2; ++q) {
            const float* plane = planeA + q * (HH * WW);
            #pragma unroll
            for (int r = 0; r < 10; ++r) {
                const int row = h0 - 1 + r;
                const bool valid = (row >= 0) && (row < HH);
                const int rrow = row < 0 ? 0 : (row >= HH ? HH - 1 : row);
                const float* rp = plane + rrow * WW + gw;
                f32x4_t M = *(const f32x4_t*)rp;
                float vl = rp[l_edge ? 0 : -1];
                float vr = rp[r_edge ? 3 : 4];
                xd[q][r][0] = (valid && !l_edge) ? vl : 0.f;
                xd[q][r][1] = valid ? M.x : 0.f;
                xd[q][r][2] = valid ? M.y : 0.f;
                xd[q][r][3] = valid ? M.z : 0.f;
                xd[q][r][4] = valid ? M.w : 0.f;
                xd[q][r][5] = (valid && !r_edge) ? vr : 0.f;
            }
        }
        #pragma unroll
        for (int py = 0; py < 8; ++py) {
            #pragma unroll
            for (int i = 0; i < 4; ++i) {
                float sA = 0.f, sB = 0.f;
                #pragma unroll
                for (int t = 0; t < 3; ++t) {
                    sA = fmaf(xd[0][py + 0][i + t], kwA[t],     sA);
                    sA = fmaf(xd[0][py + 1][i + t], kwA[3 + t], sA);
                    sA = fmaf(xd[0][py + 2][i + t], kwA[6 + t], sA);
                    sB = fmaf(xd[1][py + 0][i + t], kwB[t],     sB);
                    sB = fmaf(xd[1][py + 1][i + t], kwB[3 + t], sB);
                    sB = fmaf(xd[1][py + 2][i + t], kwB[6 + t], sB);
                }
                __hip_bfloat16 hA = __float2bfloat16(sA);
                __hip_bfloat16 hB = __float2bfloat16(sB);
                unsigned pk = (unsigned)*reinterpret_cast<unsigned short*>(&hA)
                            | ((unsigned)*reinterpret_cast<unsigned short*>(&hB) << 16);
                const int p = py * 16 + wq * 4 + i;
                const unsigned boff = ((unsigned)(cp << 2)) ^ (((unsigned)p & 7u) << 4);
                *reinterpret_cast<unsigned*>(&xnb[(unsigned)p * 256 + boff]) = pk;
            }
        }
    }
    __syncthreads();
    {
        const int lane   = tid & 63;
        const int wv     = tid >> 6;
        const int lo     = lane & 15;
        const int hi     = lane >> 4;
        const int o_base = wv * 32;
        bf16x8_t afrag[2][4];
        #pragma unroll
        for (int t2 = 0; t2 < 2; ++t2)
            #pragma unroll
            for (int kc = 0; kc < 4; ++kc)
                afrag[t2][kc] = *reinterpret_cast<const bf16x8_t*>(
                    wper + (size_t)(o_base + t2 * 16 + lo) * CC + kc * 32 + hi * 8);
        f32x4_t acc[8][2];
        #pragma unroll
        for (int pt = 0; pt < 8; ++pt) {
            acc[pt][0] = (f32x4_t){0.f, 0.f, 0.f, 0.f};
            acc[pt][1] = (f32x4_t){0.f, 0.f, 0.f, 0.f};
        }
        #pragma unroll
        for (int pt = 0; pt < 8; ++pt) {
            const unsigned rowbase = (unsigned)(pt * 16 + lo) * 256;
            const unsigned sw = (unsigned)((lo & 7) << 4);
            #pragma unroll
            for (int kc = 0; kc < 4; ++kc) {
                bf16x8_t bfrag = *reinterpret_cast<const bf16x8_t*>(
                    &xnb[rowbase + (((unsigned)(kc * 64 + hi * 16)) ^ sw)]);
                acc[pt][0] = __builtin_amdgcn_mfma_f32_16x16x32_bf16(
                    afrag[0][kc], bfrag, acc[pt][0], 0, 0, 0);
                acc[pt][1] = __builtin_amdgcn_mfma_f32_16x16x32_bf16(
                    afrag[1][kc], bfrag, acc[pt][1], 0, 0, 0);
            }
        }
        float iv[2][4], bs[2][4];
        #pragma unroll
        for (int t2 = 0; t2 < 2; ++t2)
            #pragma unroll
            for (int r = 0; r < 4; ++r) {
                const int o = o_base + t2 * 16 + hi * 4 + r;
                iv[t2][r] = invp[o];
                bs[t2][r] = biasp[o];
            }
        #pragma unroll
        for (int pt = 0; pt < 8; ++pt) {
            const int hrow = h0 + pt;
            #pragma unroll
            for (int t2 = 0; t2 < 2; ++t2) {
                #pragma unroll
                for (int r = 0; r < 4; ++r) {
                    const int o = o_base + t2 * 16 + hi * 4 + r;
                    float val = fmaf(acc[pt][t2][r], iv[t2][r], bs[t2][r]);
                    val = fmaxf(val, 0.f);
                    out[((size_t)(bb * CC + o) * HH + hrow) * WW + w0 + lo] = val;
                }
            }
        }
    }
}

extern "C" void kernel_launch(void* const* d_in, const int* in_sizes, int n_in,
                              void* d_out, int out_size, void* d_ws, size_t ws_size,
                              hipStream_t stream) {
    const float* x   = (const float*)d_in[0];
    const float* kk  = (const float*)d_in[1];
    const float* pwt = (const float*)d_in[2];
    const float* g   = (const float*)d_in[3];
    const float* b   = (const float*)d_in[4];
    const float* m   = (const float*)d_in[5];
    const float* v   = (const float*)d_in[6];
    float* out = (float*)d_out;

    unsigned short* wper = (unsigned short*)d_ws;                 // 32 KB
    float* inv  = (float*)((char*)d_ws + 32768);                  // 512 B
    float* bias = (float*)((char*)d_ws + 32768 + 512);            // 512 B
    unsigned short* xn = (unsigned short*)((char*)d_ws + 36864);  // 75.5 MB
    const size_t need = 36864 + (size_t)BB * CC * HH * WW * 2;

    if (ws_size >= need) {
        dw_kernel<<<dim3(1024), 256, 0, stream>>>(x, kk, pwt, g, b, m, v,
                                                  wper, inv, bias, xn);
        pw_kernel<<<dim3(768), 256, 0, stream>>>(xn, wper, inv, bias, out);
    } else {
        prep_kernel<<<64, 256, 0, stream>>>(pwt, g, b, m, v, wper, inv, bias);
        fused_main<<<dim3(2304), 256, 0, stream>>>(x, kk, wper, inv, bias, out);
    }
}